// Round 12
// baseline (286.125 us; speedup 1.0000x reference)
//
#include <hip/hip_runtime.h>
#include <math.h>

#define D  32
#define BN 16384
#define PP 16

typedef __bf16 bf16x8 __attribute__((ext_vector_type(8)));
typedef __bf16 bf16x4 __attribute__((ext_vector_type(4)));
typedef float  floatx4 __attribute__((ext_vector_type(4)));

#define K1 1.44269504088896341f      // log2(e)
#define K2 2.88539008177792681f      // 2*log2(e)

// Per-hop image (bytes), all bf16 matrices in MFMA A-layout [gate row][k]:
//   Whh  128 x 32 (stride 34 elems)  -> LDS
//   Tr'  128 x 32 (stride 34): Tr'[g][j] = Wih[g][0:32]@rel[j]      (no bias)
//   Te'  128 x 32 (stride 34): Te'[g][k] = Wih[g][32:64]@ent[k] + bias[g]
//   Wu   128 x 32 (stride 32, packed) -> stays in GLOBAL (step-0 only)
#define WHH_OFF   0
#define TR_OFF    8704
#define TE_OFF    17408
#define LDS_IMG   26112
#define WU_OFF    26112
#define IMG_BYTES 34304
// H: 4 waves x 2 chains x 16 pairs x 72 B (stride 18 words -> 2-way free)
#define LDS_BYTES (LDS_IMG + 8 * 1152)

__device__ __forceinline__ float sigf(float x) {
    float e = __builtin_amdgcn_exp2f(-x * K1);
    return __builtin_amdgcn_rcpf(1.0f + e);
}
__device__ __forceinline__ float logsigf(float x) {
    float ax = fabsf(x);
    float l = log1pf(__expf(-ax));
    return (x >= 0.0f) ? -l : x - l;
}
__device__ __forceinline__ bf16x8 loadu8(const float* __restrict__ p) {
    float4 a = ((const float4*)p)[0], b = ((const float4*)p)[1];
    bf16x8 r = { (__bf16)a.x, (__bf16)a.y, (__bf16)a.z, (__bf16)a.w,
                 (__bf16)b.x, (__bf16)b.y, (__bf16)b.z, (__bf16)b.w };
    return r;
}
// one-hot B-fragment: B[k=8q+i][n] = (8q+i == j) (per-lane j)
__device__ __forceinline__ bf16x8 onehot(int j, int q) {
    bf16x8 r;
    #pragma unroll
    for (int i = 0; i < 8; ++i)
        r[i] = (8 * q + i == j) ? (__bf16)1.0f : (__bf16)0.0f;
    return r;
}

// ---------------------------------------------------------------------------
__global__ __launch_bounds__(256)
void prep_tables(const float* __restrict__ ent, const float* __restrict__ rel,
                 const float* __restrict__ wih0, const float* __restrict__ whh0,
                 const float* __restrict__ bih0, const float* __restrict__ bhh0,
                 const float* __restrict__ wih1, const float* __restrict__ whh1,
                 const float* __restrict__ bih1, const float* __restrict__ bhh1,
                 float* __restrict__ imgs_f)
{
    const int id = blockIdx.x * 256 + threadIdx.x;   // 128 blocks -> 32768
    if (id < 16384) {                                // Tr'/Te' entries
        const int hop = id >> 13;
        const int rest = id & 8191;
        const int tab = rest >> 12;                  // 0 = Tr', 1 = Te'
        const int k   = (rest >> 7) & 31;
        const int g   = rest & 127;
        const float* wih = hop ? wih1 : wih0;
        char* base = (char*)imgs_f + (size_t)hop * IMG_BYTES;
        if (tab == 0) {
            const float* w = wih + (size_t)g * 64;        // cols 0..31
            const float* s = rel + (size_t)k * 32;
            float a = 0.0f;
            #pragma unroll
            for (int d = 0; d < 32; ++d) a = fmaf(w[d], s[d], a);
            *((__bf16*)(base + TR_OFF) + g * 34 + k) = (__bf16)a;
        } else {
            const float* w = wih + (size_t)g * 64 + 32;   // cols 32..63
            const float* s = ent + (size_t)k * 32;
            float a = hop ? (bih1[g] + bhh1[g]) : (bih0[g] + bhh0[g]);
            #pragma unroll
            for (int d = 0; d < 32; ++d) a = fmaf(w[d], s[d], a);
            *((__bf16*)(base + TE_OFF) + g * 34 + k) = (__bf16)a;
        }
    } else {                                         // Wu / Whh images
        const int id2 = id - 16384;
        const int hop = id2 >> 13;
        const int rest = id2 & 8191;
        const int mat  = rest >> 12;                 // 0 = Wu, 1 = Whh
        const int e    = rest & 4095;
        const int gate = e >> 5, d = e & 31;
        char* base = (char*)imgs_f + (size_t)hop * IMG_BYTES;
        if (mat == 0) {
            float v = (hop ? wih1 : wih0)[(size_t)gate * 64 + d];
            *((__bf16*)(base + WU_OFF) + gate * 32 + d) = (__bf16)v;
        } else {
            float v = (hop ? whh1 : whh0)[(size_t)gate * 32 + d];
            *((__bf16*)(base + WHH_OFF) + gate * 34 + d) = (__bf16)v;
        }
    }
}

// nonlin in C-layout D[gate][pair]: lane (q=lane>>4, p=lane&15), tile mt holds
// gates 16mt+4q+r of pair p -> unit quartets hf=0: 4q+r, hf=1: 16+4q+r.
template<bool FIRST, bool LAST>
__device__ __forceinline__ void nonlin(
    floatx4* __restrict__ acc, float* __restrict__ cst,
    float* __restrict__ hlo, float* __restrict__ hhi,
    char* __restrict__ Hw, int q, int bnl)
{
    #pragma unroll
    for (int hf = 0; hf < 2; ++hf) {
        float* hout = hf ? hhi : hlo;
        #pragma unroll
        for (int r = 0; r < 4; ++r) {
            float gi = acc[0 + hf][r], gf = acc[2 + hf][r],
                  gg = acc[4 + hf][r], go = acc[6 + hf][r];
            float Ai = 1.0f + __builtin_amdgcn_exp2f(-gi * K1);
            float Af = 1.0f + __builtin_amdgcn_exp2f(-gf * K1);
            float G2 = __builtin_amdgcn_exp2f(gg * K2);
            float Gp = G2 + 1.0f, Gm = G2 - 1.0f;
            float cold = FIRST ? 0.0f : cst[hf * 4 + r];
            float num = cold * Ai * Gp + Gm * Af;
            float c = num * __builtin_amdgcn_rcpf(Af * Ai * Gp);
            cst[hf * 4 + r] = c;
            float Ao = 1.0f + __builtin_amdgcn_exp2f(-go * K1);
            float C2 = __builtin_amdgcn_exp2f(c * K2);
            hout[r] = (C2 - 1.0f) * __builtin_amdgcn_rcpf(Ao * (C2 + 1.0f));
        }
    }
    if (!LAST) {
        bf16x4 plo = { (__bf16)hlo[0], (__bf16)hlo[1], (__bf16)hlo[2], (__bf16)hlo[3] };
        bf16x4 phi = { (__bf16)hhi[0], (__bf16)hhi[1], (__bf16)hhi[2], (__bf16)hhi[3] };
        *(bf16x4*)(Hw + bnl * 72 + 8 * q)      = plo;   // units 4q..4q+3
        *(bf16x4*)(Hw + bnl * 72 + 32 + 8 * q) = phi;   // units 16+4q..+3
    }
}

// Grid 4096: hop = bid&1, idx = bid>>1. 4 waves x 2 chains (batches idx*8+w,
// +4). Acc-init via one-hot MFMA selection from Tr'/Te' (idle MFMA pipe) —
// no table ds_reads, no cvt/add VALU. Per wave-step: 4 one-hots, 24 A-frag
// b128 reads (shared across chains), 48 MFMAs, trans chain, H via LDS.
__global__ __launch_bounds__(256, 4)
void hop_mfma(const float* __restrict__ user_table,
              const int*   __restrict__ users,
              const int*   __restrict__ items,
              const int*   __restrict__ lp0,     // (NE,P,3)
              const int*   __restrict__ lp1,     // (NE,P,5)
              const float* __restrict__ imgs_f,
              float* __restrict__ F0,            // (B,32) sum_p h
              float* __restrict__ F1)
{
    __shared__ __align__(16) char lds[LDS_BYTES];

    const bool second = blockIdx.x & 1;
    const int  idx    = blockIdx.x >> 1;
    const int tid  = threadIdx.x;
    const int lane = tid & 63;
    const int wave = tid >> 6;
    const int q    = lane >> 4;
    const int bnl  = lane & 15;

    const char* imgG = (const char*)imgs_f + (second ? IMG_BYTES : 0);

    // ---- image (Whh, Tr', Te') -> LDS --------------------------------------
    {
        const float4* g = (const float4*)imgG;
        float4* l = (float4*)lds;
        #pragma unroll
        for (int i = 0; i < 7; ++i) {
            int k = i * 256 + tid;                 // LDS_IMG/16 = 1632
            if (k < LDS_IMG / 16) l[k] = g[k];
        }
    }

    // ---- Wu A-frags straight from global (step-0 only, L2-hot 8 KB) --------
    bf16x8 WuF[8];
    {
        const __bf16* wu = (const __bf16*)(imgG + WU_OFF);
        #pragma unroll
        for (int mt = 0; mt < 8; ++mt)
            WuF[mt] = *(const bf16x8*)(wu + (16 * mt + bnl) * 32 + q * 8);
    }

    // ---- per-chain setup ---------------------------------------------------
    const int fbA = idx * 8 + wave;
    const int fbB = fbA + 4;
    const int L   = second ? 5 : 3;
    const int* lp = second ? lp1 : lp0;
    const int* __restrict__ ilA = lp + ((size_t)items[fbA] * PP + bnl) * L;
    const int* __restrict__ ilB = lp + ((size_t)items[fbB] * PP + bnl) * L;

    bf16x8 buA = loadu8(user_table + (size_t)users[fbA] * D + q * 8);
    bf16x8 buB = loadu8(user_table + (size_t)users[fbB] * D + q * 8);

    __syncthreads();   // image ready

    const char* Whh = lds + WHH_OFF;
    const char* Tr  = lds + TR_OFF;
    const char* Te  = lds + TE_OFF;
    char* HwA = lds + LDS_IMG + (wave * 2 + 0) * 1152;
    char* HwB = lds + LDS_IMG + (wave * 2 + 1) * 1152;

    float cstA[8], cstB[8], hloA[4], hhiA[4], hloB[4], hhiB[4];

    // ---- step 0: acc = Te'[seed] (one-hot) + Wu @ u ------------------------
    {
        bf16x8 ohA = onehot(ilA[0], q);
        bf16x8 ohB = onehot(ilB[0], q);
        floatx4 accA[8], accB[8];
        #pragma unroll
        for (int mt = 0; mt < 8; ++mt) {
            bf16x8 teF = *(const bf16x8*)(Te + (16 * mt + bnl) * 68 + q * 16);
            floatx4 z = { 0.f, 0.f, 0.f, 0.f };
            accA[mt] = __builtin_amdgcn_mfma_f32_16x16x32_bf16(teF, ohA, z, 0, 0, 0);
            accB[mt] = __builtin_amdgcn_mfma_f32_16x16x32_bf16(teF, ohB, z, 0, 0, 0);
            accA[mt] = __builtin_amdgcn_mfma_f32_16x16x32_bf16(WuF[mt], buA, accA[mt], 0, 0, 0);
            accB[mt] = __builtin_amdgcn_mfma_f32_16x16x32_bf16(WuF[mt], buB, accB[mt], 0, 0, 0);
        }
        nonlin<true, false>(accA, cstA, hloA, hhiA, HwA, q, bnl);
        nonlin<true, false>(accB, cstB, hloB, hhiB, HwB, q, bnl);
    }

    // ---- steps 1..T-1: acc = Tr'[j] + Te'[k] + Whh @ h ---------------------
    #pragma unroll
    for (int t = 1; t < 3; ++t) {
        if (t == 2 && !second) break;
        const bool last = (t == (second ? 2 : 1));
        bf16x8 ojA = onehot(ilA[2 * t - 1], q);
        bf16x8 okA = onehot(ilA[2 * t], q);
        bf16x8 ojB = onehot(ilB[2 * t - 1], q);
        bf16x8 okB = onehot(ilB[2 * t], q);
        bf16x8 bhA = *(const bf16x8*)(HwA + bnl * 72 + q * 16);
        bf16x8 bhB = *(const bf16x8*)(HwB + bnl * 72 + q * 16);
        floatx4 accA[8], accB[8];
        #pragma unroll
        for (int mt = 0; mt < 8; ++mt) {
            const int ro = (16 * mt + bnl) * 68 + q * 16;
            bf16x8 trF = *(const bf16x8*)(Tr + ro);
            bf16x8 teF = *(const bf16x8*)(Te + ro);
            bf16x8 whF = *(const bf16x8*)(Whh + ro);
            floatx4 z = { 0.f, 0.f, 0.f, 0.f };
            floatx4 a = __builtin_amdgcn_mfma_f32_16x16x32_bf16(trF, ojA, z, 0, 0, 0);
            floatx4 b = __builtin_amdgcn_mfma_f32_16x16x32_bf16(trF, ojB, z, 0, 0, 0);
            a = __builtin_amdgcn_mfma_f32_16x16x32_bf16(teF, okA, a, 0, 0, 0);
            b = __builtin_amdgcn_mfma_f32_16x16x32_bf16(teF, okB, b, 0, 0, 0);
            a = __builtin_amdgcn_mfma_f32_16x16x32_bf16(whF, bhA, a, 0, 0, 0);
            b = __builtin_amdgcn_mfma_f32_16x16x32_bf16(whF, bhB, b, 0, 0, 0);
            accA[mt] = a;
            accB[mt] = b;
        }
        if (last) {
            nonlin<false, true>(accA, cstA, hloA, hhiA, HwA, q, bnl);
            nonlin<false, true>(accB, cstB, hloB, hhiB, HwB, q, bnl);
        } else {
            nonlin<false, false>(accA, cstA, hloA, hhiA, HwA, q, bnl);
            nonlin<false, false>(accB, cstB, hloB, hhiB, HwB, q, bnl);
        }
    }

    // ---- sum over pairs (reduce across bnl lanes), write F -----------------
    #pragma unroll
    for (int r = 0; r < 4; ++r) {
        #pragma unroll
        for (int m = 1; m < 16; m <<= 1) {
            hloA[r] += __shfl_xor(hloA[r], m);
            hhiA[r] += __shfl_xor(hhiA[r], m);
            hloB[r] += __shfl_xor(hloB[r], m);
            hhiB[r] += __shfl_xor(hhiB[r], m);
        }
    }
    if (bnl == 0) {
        float* Fout = (second ? F1 : F0);
        float4 vloA = { hloA[0], hloA[1], hloA[2], hloA[3] };
        float4 vhiA = { hhiA[0], hhiA[1], hhiA[2], hhiA[3] };
        float4 vloB = { hloB[0], hloB[1], hloB[2], hloB[3] };
        float4 vhiB = { hhiB[0], hhiB[1], hhiB[2], hhiB[3] };
        *(float4*)(Fout + (size_t)fbA * D + 4 * q)      = vloA;
        *(float4*)(Fout + (size_t)fbA * D + 16 + 4 * q) = vhiA;
        *(float4*)(Fout + (size_t)fbB * D + 4 * q)      = vloB;
        *(float4*)(Fout + (size_t)fbB * D + 16 + 4 * q) = vhiB;
    }
}

// Per b: emb0=(ent[items]+F0)@W^T+b ; emb1=(emb0+F1)@W^T+b ; score=dot(u,emb1)
__global__ __launch_bounds__(256)
void chain_score(const float* __restrict__ user_table,
                 const float* __restrict__ ent_table,
                 const float* __restrict__ agg_w,
                 const float* __restrict__ agg_b,
                 const int*   __restrict__ users,
                 const int*   __restrict__ items,
                 const int*   __restrict__ ratings,
                 const float* __restrict__ F0,
                 const float* __restrict__ F1,
                 float* __restrict__ out,
                 float* __restrict__ partials)
{
    __shared__ float s[8][33];
    __shared__ float red[8];
    const int tid = threadIdx.x;
    const int bb  = tid >> 5;
    const int j   = tid & 31;
    const int b   = blockIdx.x * 8 + bb;
    const int it  = items[b];

    s[bb][j] = ent_table[(size_t)it * D + j] + F0[(size_t)b * D + j];
    __syncthreads();
    const float* __restrict__ w = agg_w + (size_t)j * D;
    float e0 = agg_b[j];
    #pragma unroll
    for (int k = 0; k < D; ++k) e0 = fmaf(s[bb][k], w[k], e0);
    __syncthreads();
    s[bb][j] = e0 + F1[(size_t)b * D + j];
    __syncthreads();
    float e1 = agg_b[j];
    #pragma unroll
    for (int k = 0; k < D; ++k) e1 = fmaf(s[bb][k], w[k], e1);

    float prod = user_table[(size_t)users[b] * D + j] * e1;
    #pragma unroll
    for (int m = 1; m < 32; m <<= 1) prod += __shfl_xor(prod, m);
    if (j == 0) {
        out[1 + b]      = sigf(prod);
        out[1 + BN + b] = (float)it;
        float r = (float)ratings[b];
        red[bb] = r * logsigf(prod) + (1.0f - r) * logsigf(-prod);
    }
    __syncthreads();
    if (tid == 0) {
        float t = 0.0f;
        #pragma unroll
        for (int qq = 0; qq < 8; ++qq) t += red[qq];
        partials[blockIdx.x] = t;
    }
}

__global__ __launch_bounds__(256)
void loss_kernel(const float* __restrict__ partials, float* __restrict__ out)
{
    __shared__ float red[4];
    const int t = threadIdx.x;
    float v = 0.0f;
    #pragma unroll
    for (int qq = 0; qq < 8; ++qq) v += partials[qq * 256 + t];
    #pragma unroll
    for (int m = 1; m < 64; m <<= 1) v += __shfl_xor(v, m);
    if ((t & 63) == 0) red[t >> 6] = v;
    __syncthreads();
    if (t == 0) out[0] = -(red[0] + red[1] + red[2] + red[3]) / (float)BN;
}

extern "C" void kernel_launch(void* const* d_in, const int* in_sizes, int n_in,
                              void* d_out, int out_size, void* d_ws, size_t ws_size,
                              hipStream_t stream)
{
    const float* user_table = (const float*)d_in[0];
    const float* ent_table  = (const float*)d_in[1];
    const float* rel_table  = (const float*)d_in[2];
    const float* w_ih0 = (const float*)d_in[3];
    const float* w_hh0 = (const float*)d_in[4];
    const float* b_ih0 = (const float*)d_in[5];
    const float* b_hh0 = (const float*)d_in[6];
    const float* w_ih1 = (const float*)d_in[7];
    const float* w_hh1 = (const float*)d_in[8];
    const float* b_ih1 = (const float*)d_in[9];
    const float* b_hh1 = (const float*)d_in[10];
    const float* agg_w = (const float*)d_in[11];
    const float* agg_b = (const float*)d_in[12];
    const int* users   = (const int*)d_in[13];
    const int* items   = (const int*)d_in[14];
    const int* ratings = (const int*)d_in[15];
    const int* lp0     = (const int*)d_in[16];
    const int* lp1     = (const int*)d_in[17];
    float* out = (float*)d_out;

    float* ws       = (float*)d_ws;
    float* F0       = ws;                              // BN*32
    float* F1       = ws + (size_t)BN * D;             // BN*32
    float* partials = ws + 2 * (size_t)BN * D;         // 2048
    float* imgs     = ws + 2 * (size_t)BN * D + 2048;  // 2 x IMG_BYTES

    prep_tables<<<128, 256, 0, stream>>>(ent_table, rel_table,
        w_ih0, w_hh0, b_ih0, b_hh0, w_ih1, w_hh1, b_ih1, b_hh1, imgs);
    hop_mfma<<<4096, 256, 0, stream>>>(
        user_table, users, items, lp0, lp1, imgs, F0, F1);
    chain_score<<<BN / 8, 256, 0, stream>>>(
        user_table, ent_table, agg_w, agg_b, users, items, ratings,
        F0, F1, out, partials);
    loss_kernel<<<1, 256, 0, stream>>>(partials, out);
}

// Round 13
// 284.401 us; speedup vs baseline: 1.0061x; 1.0061x over previous
//
#include <hip/hip_runtime.h>
#include <math.h>

#define D  32
#define BN 16384
#define PP 16

typedef __bf16 bf16x8 __attribute__((ext_vector_type(8)));
typedef __bf16 bf16x4 __attribute__((ext_vector_type(4)));
typedef float  floatx4 __attribute__((ext_vector_type(4)));

#define K1 1.44269504088896341f      // log2(e)
#define K2 2.88539008177792681f      // 2*log2(e)

// Per-hop image (bytes), bf16 matrices in MFMA A-layout [gate row][k]:
//   Whh  128 x 32 (stride 34 elems)  -> LDS   (conflict-free: bank=17*row%32)
//   Tr'  128 x 32 (stride 34): Tr'[g][j] = Wih[g][0:32]@rel[j]      (no bias)
//   Te'  128 x 32 (stride 34): Te'[g][k] = Wih[g][32:64]@ent[k] + bias[g]
//   Wu   128 x 32 (stride 32, packed) -> stays in GLOBAL (step-0 only)
#define WHH_OFF   0
#define TR_OFF    8704
#define TE_OFF    17408
#define LDS_IMG   26112
#define WU_OFF    26112
#define IMG_BYTES 34304
// H: 4 waves x 2 chains x 16 pairs x 72 B
#define LDS_BYTES (LDS_IMG + 8 * 1152)

__device__ __forceinline__ float sigf(float x) {
    float e = __builtin_amdgcn_exp2f(-x * K1);
    return __builtin_amdgcn_rcpf(1.0f + e);
}
__device__ __forceinline__ float logsigf(float x) {
    float ax = fabsf(x);
    float l = log1pf(__expf(-ax));
    return (x >= 0.0f) ? -l : x - l;
}
__device__ __forceinline__ bf16x8 loadu8(const float* __restrict__ p) {
    float4 a = ((const float4*)p)[0], b = ((const float4*)p)[1];
    bf16x8 r = { (__bf16)a.x, (__bf16)a.y, (__bf16)a.z, (__bf16)a.w,
                 (__bf16)b.x, (__bf16)b.y, (__bf16)b.z, (__bf16)b.w };
    return r;
}
// one-hot B-fragment: B[k=8q+i][n] = (8q+i == j) (per-lane j)
__device__ __forceinline__ bf16x8 onehot(int j, int q) {
    bf16x8 r;
    #pragma unroll
    for (int i = 0; i < 8; ++i)
        r[i] = (8 * q + i == j) ? (__bf16)1.0f : (__bf16)0.0f;
    return r;
}

// ---------------------------------------------------------------------------
__global__ __launch_bounds__(256)
void prep_tables(const float* __restrict__ ent, const float* __restrict__ rel,
                 const float* __restrict__ wih0, const float* __restrict__ whh0,
                 const float* __restrict__ bih0, const float* __restrict__ bhh0,
                 const float* __restrict__ wih1, const float* __restrict__ whh1,
                 const float* __restrict__ bih1, const float* __restrict__ bhh1,
                 float* __restrict__ imgs_f)
{
    const int id = blockIdx.x * 256 + threadIdx.x;   // 128 blocks -> 32768
    if (id < 16384) {                                // Tr'/Te' entries
        const int hop = id >> 13;
        const int rest = id & 8191;
        const int tab = rest >> 12;                  // 0 = Tr', 1 = Te'
        const int k   = (rest >> 7) & 31;
        const int g   = rest & 127;
        const float* wih = hop ? wih1 : wih0;
        char* base = (char*)imgs_f + (size_t)hop * IMG_BYTES;
        if (tab == 0) {
            const float* w = wih + (size_t)g * 64;        // cols 0..31
            const float* s = rel + (size_t)k * 32;
            float a = 0.0f;
            #pragma unroll
            for (int d = 0; d < 32; ++d) a = fmaf(w[d], s[d], a);
            *((__bf16*)(base + TR_OFF) + g * 34 + k) = (__bf16)a;
        } else {
            const float* w = wih + (size_t)g * 64 + 32;   // cols 32..63
            const float* s = ent + (size_t)k * 32;
            float a = hop ? (bih1[g] + bhh1[g]) : (bih0[g] + bhh0[g]);
            #pragma unroll
            for (int d = 0; d < 32; ++d) a = fmaf(w[d], s[d], a);
            *((__bf16*)(base + TE_OFF) + g * 34 + k) = (__bf16)a;
        }
    } else {                                         // Wu / Whh images
        const int id2 = id - 16384;
        const int hop = id2 >> 13;
        const int rest = id2 & 8191;
        const int mat  = rest >> 12;                 // 0 = Wu, 1 = Whh
        const int e    = rest & 4095;
        const int gate = e >> 5, d = e & 31;
        char* base = (char*)imgs_f + (size_t)hop * IMG_BYTES;
        if (mat == 0) {
            float v = (hop ? wih1 : wih0)[(size_t)gate * 64 + d];
            *((__bf16*)(base + WU_OFF) + gate * 32 + d) = (__bf16)v;
        } else {
            float v = (hop ? whh1 : whh0)[(size_t)gate * 32 + d];
            *((__bf16*)(base + WHH_OFF) + gate * 34 + d) = (__bf16)v;
        }
    }
}

// nonlin in C-layout D[gate][pair]: lane (q=lane>>4, p=lane&15), tile mt holds
// gates 16mt+4q+r of pair p -> unit quartets hf=0: 4q+r, hf=1: 16+4q+r.
template<bool FIRST, bool LAST>
__device__ __forceinline__ void nonlin(
    floatx4* __restrict__ acc, float* __restrict__ cst,
    float* __restrict__ hlo, float* __restrict__ hhi,
    char* __restrict__ Hw, int q, int bnl)
{
    #pragma unroll
    for (int hf = 0; hf < 2; ++hf) {
        float* hout = hf ? hhi : hlo;
        #pragma unroll
        for (int r = 0; r < 4; ++r) {
            float gi = acc[0 + hf][r], gf = acc[2 + hf][r],
                  gg = acc[4 + hf][r], go = acc[6 + hf][r];
            float Ai = 1.0f + __builtin_amdgcn_exp2f(-gi * K1);
            float Af = 1.0f + __builtin_amdgcn_exp2f(-gf * K1);
            float G2 = __builtin_amdgcn_exp2f(gg * K2);
            float Gp = G2 + 1.0f, Gm = G2 - 1.0f;
            float cold = FIRST ? 0.0f : cst[hf * 4 + r];
            float num = cold * Ai * Gp + Gm * Af;
            float c = num * __builtin_amdgcn_rcpf(Af * Ai * Gp);
            cst[hf * 4 + r] = c;
            float Ao = 1.0f + __builtin_amdgcn_exp2f(-go * K1);
            float C2 = __builtin_amdgcn_exp2f(c * K2);
            hout[r] = (C2 - 1.0f) * __builtin_amdgcn_rcpf(Ao * (C2 + 1.0f));
        }
    }
    if (!LAST) {
        bf16x4 plo = { (__bf16)hlo[0], (__bf16)hlo[1], (__bf16)hlo[2], (__bf16)hlo[3] };
        bf16x4 phi = { (__bf16)hhi[0], (__bf16)hhi[1], (__bf16)hhi[2], (__bf16)hhi[3] };
        *(bf16x4*)(Hw + bnl * 72 + 8 * q)      = plo;   // units 4q..4q+3
        *(bf16x4*)(Hw + bnl * 72 + 32 + 8 * q) = phi;   // units 16+4q..+3
    }
}

// Grid 4096: hop = bid&1, idx = bid>>1. 4 waves x 2 chains (batches idx*8+w,
// +4). Acc-init via one-hot MFMA selection from Tr'/Te' (idle MFMA pipe).
// (256,3): R7/R12 lesson — tight bounds + big live state = spill. No hoists.
__global__ __launch_bounds__(256, 3)
void hop_mfma(const float* __restrict__ user_table,
              const int*   __restrict__ users,
              const int*   __restrict__ items,
              const int*   __restrict__ lp0,     // (NE,P,3)
              const int*   __restrict__ lp1,     // (NE,P,5)
              const float* __restrict__ imgs_f,
              float* __restrict__ F0,            // (B,32) sum_p h
              float* __restrict__ F1)
{
    __shared__ __align__(16) char lds[LDS_BYTES];

    const bool second = blockIdx.x & 1;
    const int  idx    = blockIdx.x >> 1;
    const int tid  = threadIdx.x;
    const int lane = tid & 63;
    const int wave = tid >> 6;
    const int q    = lane >> 4;
    const int bnl  = lane & 15;

    const char* imgG = (const char*)imgs_f + (second ? IMG_BYTES : 0);

    // ---- image (Whh, Tr', Te') -> LDS --------------------------------------
    {
        const float4* g = (const float4*)imgG;
        float4* l = (float4*)lds;
        #pragma unroll
        for (int i = 0; i < 7; ++i) {
            int k = i * 256 + tid;                 // LDS_IMG/16 = 1632
            if (k < LDS_IMG / 16) l[k] = g[k];
        }
    }

    // ---- per-chain setup ---------------------------------------------------
    const int fbA = idx * 8 + wave;
    const int fbB = fbA + 4;
    const int L   = second ? 5 : 3;
    const int* lp = second ? lp1 : lp0;
    const int* __restrict__ ilA = lp + ((size_t)items[fbA] * PP + bnl) * L;
    const int* __restrict__ ilB = lp + ((size_t)items[fbB] * PP + bnl) * L;

    bf16x8 buA = loadu8(user_table + (size_t)users[fbA] * D + q * 8);
    bf16x8 buB = loadu8(user_table + (size_t)users[fbB] * D + q * 8);

    __syncthreads();   // image ready

    const char* Whh = lds + WHH_OFF;
    const char* Tr  = lds + TR_OFF;
    const char* Te  = lds + TE_OFF;
    char* HwA = lds + LDS_IMG + (wave * 2 + 0) * 1152;
    char* HwB = lds + LDS_IMG + (wave * 2 + 1) * 1152;

    float cstA[8], cstB[8], hloA[4], hhiA[4], hloB[4], hhiB[4];

    // ---- step 0: acc = Te'[seed] (one-hot) + Wu @ u (Wu from global) -------
    {
        const __bf16* wu = (const __bf16*)(imgG + WU_OFF);
        bf16x8 ohA = onehot(ilA[0], q);
        bf16x8 ohB = onehot(ilB[0], q);
        floatx4 accA[8], accB[8];
        #pragma unroll
        for (int mt = 0; mt < 8; ++mt) {
            bf16x8 teF = *(const bf16x8*)(Te + (16 * mt + bnl) * 68 + q * 16);
            bf16x8 wuF = *(const bf16x8*)(wu + (16 * mt + bnl) * 32 + q * 8);
            floatx4 z = { 0.f, 0.f, 0.f, 0.f };
            floatx4 a = __builtin_amdgcn_mfma_f32_16x16x32_bf16(teF, ohA, z, 0, 0, 0);
            floatx4 b = __builtin_amdgcn_mfma_f32_16x16x32_bf16(teF, ohB, z, 0, 0, 0);
            a = __builtin_amdgcn_mfma_f32_16x16x32_bf16(wuF, buA, a, 0, 0, 0);
            b = __builtin_amdgcn_mfma_f32_16x16x32_bf16(wuF, buB, b, 0, 0, 0);
            accA[mt] = a;
            accB[mt] = b;
        }
        nonlin<true, false>(accA, cstA, hloA, hhiA, HwA, q, bnl);
        nonlin<true, false>(accB, cstB, hloB, hhiB, HwB, q, bnl);
    }

    // ---- steps 1..T-1: acc = Tr'[j] + Te'[k] + Whh @ h ---------------------
    #pragma unroll
    for (int t = 1; t < 3; ++t) {
        if (t == 2 && !second) break;
        const bool last = (t == (second ? 2 : 1));
        bf16x8 ojA = onehot(ilA[2 * t - 1], q);
        bf16x8 okA = onehot(ilA[2 * t], q);
        bf16x8 ojB = onehot(ilB[2 * t - 1], q);
        bf16x8 okB = onehot(ilB[2 * t], q);
        bf16x8 bhA = *(const bf16x8*)(HwA + bnl * 72 + q * 16);
        bf16x8 bhB = *(const bf16x8*)(HwB + bnl * 72 + q * 16);
        floatx4 accA[8], accB[8];
        #pragma unroll
        for (int mt = 0; mt < 8; ++mt) {
            const int ro = (16 * mt + bnl) * 68 + q * 16;
            bf16x8 trF = *(const bf16x8*)(Tr + ro);
            bf16x8 teF = *(const bf16x8*)(Te + ro);
            bf16x8 whF = *(const bf16x8*)(Whh + ro);
            floatx4 z = { 0.f, 0.f, 0.f, 0.f };
            floatx4 a = __builtin_amdgcn_mfma_f32_16x16x32_bf16(trF, ojA, z, 0, 0, 0);
            floatx4 b = __builtin_amdgcn_mfma_f32_16x16x32_bf16(trF, ojB, z, 0, 0, 0);
            a = __builtin_amdgcn_mfma_f32_16x16x32_bf16(teF, okA, a, 0, 0, 0);
            b = __builtin_amdgcn_mfma_f32_16x16x32_bf16(teF, okB, b, 0, 0, 0);
            a = __builtin_amdgcn_mfma_f32_16x16x32_bf16(whF, bhA, a, 0, 0, 0);
            b = __builtin_amdgcn_mfma_f32_16x16x32_bf16(whF, bhB, b, 0, 0, 0);
            accA[mt] = a;
            accB[mt] = b;
        }
        if (last) {
            nonlin<false, true>(accA, cstA, hloA, hhiA, HwA, q, bnl);
            nonlin<false, true>(accB, cstB, hloB, hhiB, HwB, q, bnl);
        } else {
            nonlin<false, false>(accA, cstA, hloA, hhiA, HwA, q, bnl);
            nonlin<false, false>(accB, cstB, hloB, hhiB, HwB, q, bnl);
        }
    }

    // ---- sum over pairs (reduce across bnl lanes), write F -----------------
    #pragma unroll
    for (int r = 0; r < 4; ++r) {
        #pragma unroll
        for (int m = 1; m < 16; m <<= 1) {
            hloA[r] += __shfl_xor(hloA[r], m);
            hhiA[r] += __shfl_xor(hhiA[r], m);
            hloB[r] += __shfl_xor(hloB[r], m);
            hhiB[r] += __shfl_xor(hhiB[r], m);
        }
    }
    if (bnl == 0) {
        float* Fout = (second ? F1 : F0);
        float4 vloA = { hloA[0], hloA[1], hloA[2], hloA[3] };
        float4 vhiA = { hhiA[0], hhiA[1], hhiA[2], hhiA[3] };
        float4 vloB = { hloB[0], hloB[1], hloB[2], hloB[3] };
        float4 vhiB = { hhiB[0], hhiB[1], hhiB[2], hhiB[3] };
        *(float4*)(Fout + (size_t)fbA * D + 4 * q)      = vloA;
        *(float4*)(Fout + (size_t)fbA * D + 16 + 4 * q) = vhiA;
        *(float4*)(Fout + (size_t)fbB * D + 4 * q)      = vloB;
        *(float4*)(Fout + (size_t)fbB * D + 16 + 4 * q) = vhiB;
    }
}

// Per b: emb0=(ent[items]+F0)@W^T+b ; emb1=(emb0+F1)@W^T+b ; score=dot(u,emb1)
__global__ __launch_bounds__(256)
void chain_score(const float* __restrict__ user_table,
                 const float* __restrict__ ent_table,
                 const float* __restrict__ agg_w,
                 const float* __restrict__ agg_b,
                 const int*   __restrict__ users,
                 const int*   __restrict__ items,
                 const int*   __restrict__ ratings,
                 const float* __restrict__ F0,
                 const float* __restrict__ F1,
                 float* __restrict__ out,
                 float* __restrict__ partials)
{
    __shared__ float s[8][33];
    __shared__ float red[8];
    const int tid = threadIdx.x;
    const int bb  = tid >> 5;
    const int j   = tid & 31;
    const int b   = blockIdx.x * 8 + bb;
    const int it  = items[b];

    s[bb][j] = ent_table[(size_t)it * D + j] + F0[(size_t)b * D + j];
    __syncthreads();
    const float* __restrict__ w = agg_w + (size_t)j * D;
    float e0 = agg_b[j];
    #pragma unroll
    for (int k = 0; k < D; ++k) e0 = fmaf(s[bb][k], w[k], e0);
    __syncthreads();
    s[bb][j] = e0 + F1[(size_t)b * D + j];
    __syncthreads();
    float e1 = agg_b[j];
    #pragma unroll
    for (int k = 0; k < D; ++k) e1 = fmaf(s[bb][k], w[k], e1);

    float prod = user_table[(size_t)users[b] * D + j] * e1;
    #pragma unroll
    for (int m = 1; m < 32; m <<= 1) prod += __shfl_xor(prod, m);
    if (j == 0) {
        out[1 + b]      = sigf(prod);
        out[1 + BN + b] = (float)it;
        float r = (float)ratings[b];
        red[bb] = r * logsigf(prod) + (1.0f - r) * logsigf(-prod);
    }
    __syncthreads();
    if (tid == 0) {
        float t = 0.0f;
        #pragma unroll
        for (int qq = 0; qq < 8; ++qq) t += red[qq];
        partials[blockIdx.x] = t;
    }
}

__global__ __launch_bounds__(256)
void loss_kernel(const float* __restrict__ partials, float* __restrict__ out)
{
    __shared__ float red[4];
    const int t = threadIdx.x;
    float v = 0.0f;
    #pragma unroll
    for (int qq = 0; qq < 8; ++qq) v += partials[qq * 256 + t];
    #pragma unroll
    for (int m = 1; m < 64; m <<= 1) v += __shfl_xor(v, m);
    if ((t & 63) == 0) red[t >> 6] = v;
    __syncthreads();
    if (t == 0) out[0] = -(red[0] + red[1] + red[2] + red[3]) / (float)BN;
}

extern "C" void kernel_launch(void* const* d_in, const int* in_sizes, int n_in,
                              void* d_out, int out_size, void* d_ws, size_t ws_size,
                              hipStream_t stream)
{
    const float* user_table = (const float*)d_in[0];
    const float* ent_table  = (const float*)d_in[1];
    const float* rel_table  = (const float*)d_in[2];
    const float* w_ih0 = (const float*)d_in[3];
    const float* w_hh0 = (const float*)d_in[4];
    const float* b_ih0 = (const float*)d_in[5];
    const float* b_hh0 = (const float*)d_in[6];
    const float* w_ih1 = (const float*)d_in[7];
    const float* w_hh1 = (const float*)d_in[8];
    const float* b_ih1 = (const float*)d_in[9];
    const float* b_hh1 = (const float*)d_in[10];
    const float* agg_w = (const float*)d_in[11];
    const float* agg_b = (const float*)d_in[12];
    const int* users   = (const int*)d_in[13];
    const int* items   = (const int*)d_in[14];
    const int* ratings = (const int*)d_in[15];
    const int* lp0     = (const int*)d_in[16];
    const int* lp1     = (const int*)d_in[17];
    float* out = (float*)d_out;

    float* ws       = (float*)d_ws;
    float* F0       = ws;                              // BN*32
    float* F1       = ws + (size_t)BN * D;             // BN*32
    float* partials = ws + 2 * (size_t)BN * D;         // 2048
    float* imgs     = ws + 2 * (size_t)BN * D + 2048;  // 2 x IMG_BYTES

    prep_tables<<<128, 256, 0, stream>>>(ent_table, rel_table,
        w_ih0, w_hh0, b_ih0, b_hh0, w_ih1, w_hh1, b_ih1, b_hh1, imgs);
    hop_mfma<<<4096, 256, 0, stream>>>(
        user_table, users, items, lp0, lp1, imgs, F0, F1);
    chain_score<<<BN / 8, 256, 0, stream>>>(
        user_table, ent_table, agg_w, agg_b, users, items, ratings,
        F0, F1, out, partials);
    loss_kernel<<<1, 256, 0, stream>>>(partials, out);
}